// Round 8
// baseline (253.176 us; speedup 1.0000x reference)
//
#include <hip/hip_runtime.h>

// ---- types / helpers -------------------------------------------------------
typedef unsigned short u16;
typedef unsigned int   u32;
typedef __attribute__((ext_vector_type(4))) u32    u32x4;
typedef __attribute__((ext_vector_type(4))) u16    u16x4;
typedef __attribute__((ext_vector_type(8))) u16    u16x8;
typedef __attribute__((ext_vector_type(8))) __bf16 bf16x8;
typedef __attribute__((ext_vector_type(4))) float  f32x4;

#define LOG2E 1.4426950408889634f

__device__ __forceinline__ float bf2f(u16 x) {
    u32 u = ((u32)x) << 16;
    return __builtin_bit_cast(float, u);
}
__device__ __forceinline__ u16 f2bf(float f) {  // RNE
    u32 u = __builtin_bit_cast(u32, f);
    return (u16)((u + 0x7FFFu + ((u >> 16) & 1u)) >> 16);
}
__device__ __forceinline__ u32 pk2(float a, float b) {
#if __has_builtin(__builtin_amdgcn_cvt_pk_bf16_f32)
    return __builtin_bit_cast(u32, __builtin_amdgcn_cvt_pk_bf16_f32(a, b));
#else
    return (u32)f2bf(a) | ((u32)f2bf(b) << 16);
#endif
}
__device__ __forceinline__ u16x4 pack4(f32x4 v) {
    u32 lo = pk2(v[0], v[1]), hi = pk2(v[2], v[3]);
    u32 both[2] = {lo, hi};
    return __builtin_bit_cast(u16x4, *(unsigned long long*)both);
}
__device__ __forceinline__ float fexp2(float x) {
#if __has_builtin(__builtin_amdgcn_exp2f)
    return __builtin_amdgcn_exp2f(x);
#else
    float r;
    asm("v_exp_f32 %0, %1" : "=v"(r) : "v"(x));
    return r;
#endif
}
__device__ __forceinline__ bf16x8 ldfrag(const u16* p) {
    return __builtin_bit_cast(bf16x8, *(const u32x4*)p);
}
// async global->LDS DMA, 16 B per lane; LDS dst = base + lane*16 (wave-uniform base)
__device__ __forceinline__ void g2l16(const u16* g, u16* l) {
    __builtin_amdgcn_global_load_lds(
        (const __attribute__((address_space(1))) u32*)g,
        (__attribute__((address_space(3))) u32*)l,
        16, 0, 0);
}

// ---- kernel 0: one-shot fp32 -> bf16 conversion (Wq pre-scaled by log2e) ---
__global__ __launch_bounds__(256) void convert(
    const float* __restrict__ X,
    const float* __restrict__ Wq, const float* __restrict__ Wk,
    const float* __restrict__ Wv, const float* __restrict__ Wo,
    u16* __restrict__ Xb, u16* __restrict__ Wqb, u16* __restrict__ Wkb,
    u16* __restrict__ Wvb, u16* __restrict__ Wob)
{
    const int NX = 1572864;   // 8192*768/4
    const int NW = 147456;    // 768*768/4
    int i = blockIdx.x * 256 + threadIdx.x;
    const float* src; u16* dst; int off; float sc = 1.0f;
    if (i < NX)               { src = X;  dst = Xb;  off = i; }
    else if (i < NX + NW)     { src = Wq; dst = Wqb; off = i - NX; sc = LOG2E; }
    else if (i < NX + 2 * NW) { src = Wk; dst = Wkb; off = i - NX - NW; }
    else if (i < NX + 3 * NW) { src = Wv; dst = Wvb; off = i - NX - 2 * NW; }
    else                      { src = Wo; dst = Wob; off = i - NX - 3 * NW; }
    f32x4 v = *(const f32x4*)&src[(size_t)off * 4];
    f32x4 s4 = {sc, sc, sc, sc};
    v *= s4;
    *(u16x4*)&dst[(size_t)off * 4] = pack4(v);
}

// ---- kernel 1: unified QKV GEMM (BK=32, dbuf DMA, 1 barrier/iter) ----------
// C[8192,2304] = Xb * Wcat^T. Q/K blocks compute C^T (swapped MFMA operands)
// so the head-major epilogue is b64-vectorized. V written transposed.
__global__ __launch_bounds__(256) void gemm_qkv(
    const u16* __restrict__ Xb, const u16* __restrict__ Wcat,
    const float* __restrict__ bq, const float* __restrict__ bk, const float* __restrict__ bv,
    u16* __restrict__ Qo, u16* __restrict__ Ko, u16* __restrict__ Vt)
{
    __shared__ __align__(16) u16 sA[2][128 * 32];
    __shared__ __align__(16) u16 sB[2][128 * 32];

    const int tid = threadIdx.x;
    const int wave = tid >> 6, lane = tid & 63;
    const int quad = lane >> 4, l16 = lane & 15;
    const int wr = wave >> 1, wc = wave & 1;
    const int m0 = blockIdx.x * 128;
    const int ny = blockIdx.y;            // 0..17
    const int which = ny / 6;             // 0=Q 1=K 2=V
    const int n0 = ny * 128;
    const int n_in = (ny % 6) * 128;

    // DMA coords: issue q covers rows wave*32+q*16+(lane>>2), col (lane&3)*8
    const int drow = wave * 32 + (lane >> 2);
    const int dcol = (lane & 3) * 8;
    const u16* gA = &Xb  [(size_t)(m0 + drow) * 768 + dcol];
    const u16* gB = &Wcat[(size_t)(n0 + drow) * 768 + dcol];
    u16* lA = &sA[0][wave * 1024];   // [buf] selected by +buf*4096
    u16* lB = &sB[0][wave * 1024];

    f32x4 acc[4][4] = {};

    // prologue: tile 0 -> buf 0
    g2l16(gA,            lA);
    g2l16(gA + 16 * 768, lA + 512);
    g2l16(gB,            lB);
    g2l16(gB + 16 * 768, lB + 512);

    for (int t = 0; t < 24; ++t) {
        const int buf = t & 1;
        __syncthreads();              // drains DMA(t); compute(t-1) done on buf^1
        if (t < 23) {
            const int k = (t + 1) * 32;
            u16* dA = lA + (buf ^ 1) * 4096;
            u16* dB = lB + (buf ^ 1) * 4096;
            g2l16(gA + k,            dA);
            g2l16(gA + k + 16 * 768, dA + 512);
            g2l16(gB + k,            dB);
            g2l16(gB + k + 16 * 768, dB + 512);
        }
        bf16x8 af[4], bfr[4];
#pragma unroll
        for (int i = 0; i < 4; ++i)
            af[i] = ldfrag(&sA[buf][(wr * 64 + i * 16 + l16) * 32 + quad * 8]);
#pragma unroll
        for (int j = 0; j < 4; ++j)
            bfr[j] = ldfrag(&sB[buf][(wc * 64 + j * 16 + l16) * 32 + quad * 8]);
        if (which < 2) {              // C^T: rows=n(hd-dir), cols=m(s)
#pragma unroll
            for (int i = 0; i < 4; ++i)
#pragma unroll
                for (int j = 0; j < 4; ++j)
                    acc[i][j] = __builtin_amdgcn_mfma_f32_16x16x32_bf16(bfr[j], af[i], acc[i][j], 0, 0, 0);
        } else {                      // C: rows=m(s), cols=n(hd)
#pragma unroll
            for (int i = 0; i < 4; ++i)
#pragma unroll
                for (int j = 0; j < 4; ++j)
                    acc[i][j] = __builtin_amdgcn_mfma_f32_16x16x32_bf16(af[i], bfr[j], acc[i][j], 0, 0, 0);
        }
    }

    const float* bias = (which == 0) ? bq : ((which == 1) ? bk : bv);
    if (which < 2) {
        u16* out = (which == 0) ? Qo : Ko;
        const float sc = (which == 0) ? LOG2E : 1.0f;   // W pre-scaled; bias here
        f32x4 sc4 = {sc, sc, sc, sc};
#pragma unroll
        for (int j = 0; j < 4; ++j) {
            int nb = n_in + wc * 64 + j * 16 + quad * 4;   // 4 consecutive n
            f32x4 b4 = *(const f32x4*)&bias[nb] * sc4;
            int h = nb >> 6, hd0 = nb & 63;
#pragma unroll
            for (int i = 0; i < 4; ++i) {
                int m = m0 + wr * 64 + i * 16 + l16;       // s
                int b = m >> 11, srow = m & 2047;
                *(u16x4*)&out[(((size_t)(b * 12 + h) * 2048) + srow) * 64 + hd0] =
                    pack4(acc[i][j] + b4);
            }
        }
    } else {
        // V^T [BH][64][S]: pack4 over r = s-direction
#pragma unroll
        for (int j = 0; j < 4; ++j) {
            int n = n_in + wc * 64 + j * 16 + l16;
            float bvv = bias[n];
            int h = n >> 6, hd = n & 63;
            f32x4 b4 = {bvv, bvv, bvv, bvv};
#pragma unroll
            for (int i = 0; i < 4; ++i) {
                int m = m0 + wr * 64 + i * 16 + quad * 4;
                int b = m >> 11, s = m & 2047;
                *(u16x4*)&Vt[((size_t)(b * 12 + h) * 64 + hd) * 2048 + s] = pack4(acc[i][j] + b4);
            }
        }
    }
}

// ---- kernel 2: flash attention v5 (dbuf DMA, 1 barrier/iter) ---------------
// S^T orientation; no max-tracking; L via ones-column MFMA; XCD-swizzled.
// K/Vt staged as two [64][32] planes per buffer (DMA needs unpadded rows;
// 64 B rows -> 2-way bank aliasing = free).
__global__ __launch_bounds__(256, 3) void attn(
    const u16* __restrict__ Q, const u16* __restrict__ K, const u16* __restrict__ Vt,
    u16* __restrict__ ctx)
{
    const int bid = blockIdx.x;
    const int xcd = bid & 7, slot = bid >> 3;
    const int bh = xcd * 6 + (slot % 6);      // 6 heads per XCD
    const int q0 = (slot / 6) * 128;
    const int b = bh / 12, h = bh % 12;
    const u16* Qb  = Q  + (size_t)bh * (2048 * 64);
    const u16* Kb  = K  + (size_t)bh * (2048 * 64);
    const u16* Vtb = Vt + (size_t)bh * (64 * 2048);

    __shared__ __align__(16) u16 sK [2][2][64 * 32];   // [buf][d-half][key][d32]
    __shared__ __align__(16) u16 sVt[2][2][64 * 32];   // [buf][key-half][hd][k32]
    __shared__ __align__(16) u16 sPt[128 * 72];        // [q][key], wave-private rows

    const int tid = threadIdx.x;
    const int wave = tid >> 6, lane = tid & 63;
    const int quad = lane >> 4, l16 = lane & 15;

    const int drow = lane >> 2;          // 0..15 (+wave*16)
    const int dcol = (lane & 3) * 8;

    // Q fragments direct to registers. B-operand: [n=q=l16][k=d=quad*8+j]
    bf16x8 qf[2][2];
#pragma unroll
    for (int jn = 0; jn < 2; ++jn)
#pragma unroll
        for (int ks = 0; ks < 2; ++ks)
            qf[jn][ks] = ldfrag(&Qb[(size_t)(q0 + wave * 32 + jn * 16 + l16) * 64 + ks * 32 + quad * 8]);

    bf16x8 vones;
    {
        u16x8 o;
#pragma unroll
        for (int t = 0; t < 8; ++t) o[t] = 0x3F80;
        vones = __builtin_bit_cast(bf16x8, o);
    }

    f32x4 oacc[2][4] = {};
    f32x4 Lacc[2] = {};

    // prologue: tile kt=0 -> buf 0
#pragma unroll
    for (int p = 0; p < 2; ++p) {
        g2l16(&Kb [(size_t)(wave * 16 + drow) * 64 + p * 32 + dcol],   &sK [0][p][wave * 512]);
        g2l16(&Vtb[(size_t)(wave * 16 + drow) * 2048 + p * 32 + dcol], &sVt[0][p][wave * 512]);
    }

    for (int kt = 0; kt < 2048; kt += 64) {
        const int buf = (kt >> 6) & 1;
        __syncthreads();              // drains DMA(buf); compute(prev) done on buf^1
        if (kt + 64 < 2048) {
            const int kn = kt + 64;
#pragma unroll
            for (int p = 0; p < 2; ++p) {
                g2l16(&Kb [(size_t)(kn + wave * 16 + drow) * 64 + p * 32 + dcol],
                      &sK [buf ^ 1][p][wave * 512]);
                g2l16(&Vtb[(size_t)(wave * 16 + drow) * 2048 + kn + p * 32 + dcol],
                      &sVt[buf ^ 1][p][wave * 512]);
            }
        }

        // S^T = K · Q^T : rows=key (4 tiles), cols=q (2 tiles of this wave)
        f32x4 sacc[4][2] = {};
#pragma unroll
        for (int ks = 0; ks < 2; ++ks) {
            bf16x8 kf[4];   // A-operand: [m=key=l16][k=d=quad*8+j]
#pragma unroll
            for (int i = 0; i < 4; ++i)
                kf[i] = ldfrag(&sK[buf][ks][(i * 16 + l16) * 32 + quad * 8]);
#pragma unroll
            for (int i = 0; i < 4; ++i)
#pragma unroll
                for (int jn = 0; jn < 2; ++jn)
                    sacc[i][jn] = __builtin_amdgcn_mfma_f32_16x16x32_bf16(kf[i], qf[jn][ks], sacc[i][jn], 0, 0, 0);
        }

        // exp2 (log2e folded into Q) -> P bf16 into wave-private sPt rows
#pragma unroll
        for (int i = 0; i < 4; ++i) {
#pragma unroll
            for (int jn = 0; jn < 2; ++jn) {
                f32x4 pe;
#pragma unroll
                for (int r = 0; r < 4; ++r) pe[r] = fexp2(sacc[i][jn][r]);
                *(u16x4*)&sPt[(wave * 32 + jn * 16 + l16) * 72 + i * 16 + quad * 4] = pack4(pe);
            }
        }

        // O += P · V ; L += P · 1
#pragma unroll
        for (int ks2 = 0; ks2 < 2; ++ks2) {
            bf16x8 pf[2], vf[4];
#pragma unroll
            for (int jn = 0; jn < 2; ++jn)
                pf[jn] = ldfrag(&sPt[(wave * 32 + jn * 16 + l16) * 72 + ks2 * 32 + quad * 8]);
#pragma unroll
            for (int jh = 0; jh < 4; ++jh)
                vf[jh] = ldfrag(&sVt[buf][ks2][(jh * 16 + l16) * 32 + quad * 8]);
#pragma unroll
            for (int jn = 0; jn < 2; ++jn) {
#pragma unroll
                for (int jh = 0; jh < 4; ++jh)
                    oacc[jn][jh] = __builtin_amdgcn_mfma_f32_16x16x32_bf16(pf[jn], vf[jh], oacc[jn][jh], 0, 0, 0);
                Lacc[jn] = __builtin_amdgcn_mfma_f32_16x16x32_bf16(pf[jn], vones, Lacc[jn], 0, 0, 0);
            }
        }
    }

    // epilogue: O and L share C/D layout (row q = jn*16+quad*4+r, col = l16)
#pragma unroll
    for (int jn = 0; jn < 2; ++jn) {
#pragma unroll
        for (int r = 0; r < 4; ++r) {
            float linv = 1.0f / Lacc[jn][r];
            int srow = q0 + wave * 32 + jn * 16 + quad * 4 + r;
            size_t rowbase = ((size_t)(b * 2048 + srow)) * 768 + h * 64;
#pragma unroll
            for (int jh = 0; jh < 4; ++jh)
                ctx[rowbase + jh * 16 + l16] = f2bf(oacc[jn][jh][r] * linv);
        }
    }
}

// ---- kernel 3: output projection + bias + residual (BK=32 dbuf DMA) --------
__global__ __launch_bounds__(256) void gemm_out(
    const u16* __restrict__ A,    // ctx [8192,768] bf16
    const u16* __restrict__ Wob,  // [768,768] bf16
    const float* __restrict__ bo,
    const float* __restrict__ X,  // residual fp32 (exact)
    u16* __restrict__ Hout)       // h bf16
{
    __shared__ __align__(16) u16 sA[2][128 * 32];
    __shared__ __align__(16) u16 sB[2][128 * 32];

    const int tid = threadIdx.x;
    const int wave = tid >> 6, lane = tid & 63;
    const int quad = lane >> 4, l16 = lane & 15;
    const int wr = wave >> 1, wc = wave & 1;
    const int m0 = blockIdx.x * 128, n0 = blockIdx.y * 128;

    const int drow = wave * 32 + (lane >> 2);
    const int dcol = (lane & 3) * 8;
    const u16* gA = &A  [(size_t)(m0 + drow) * 768 + dcol];
    const u16* gB = &Wob[(size_t)(n0 + drow) * 768 + dcol];
    u16* lA = &sA[0][wave * 1024];
    u16* lB = &sB[0][wave * 1024];

    f32x4 acc[4][4] = {};

    g2l16(gA,            lA);
    g2l16(gA + 16 * 768, lA + 512);
    g2l16(gB,            lB);
    g2l16(gB + 16 * 768, lB + 512);

    for (int t = 0; t < 24; ++t) {
        const int buf = t & 1;
        __syncthreads();
        if (t < 23) {
            const int k = (t + 1) * 32;
            u16* dA = lA + (buf ^ 1) * 4096;
            u16* dB = lB + (buf ^ 1) * 4096;
            g2l16(gA + k,            dA);
            g2l16(gA + k + 16 * 768, dA + 512);
            g2l16(gB + k,            dB);
            g2l16(gB + k + 16 * 768, dB + 512);
        }
        bf16x8 af[4], bfr[4];
#pragma unroll
        for (int i = 0; i < 4; ++i)
            af[i] = ldfrag(&sA[buf][(wr * 64 + i * 16 + l16) * 32 + quad * 8]);
#pragma unroll
        for (int j = 0; j < 4; ++j)
            bfr[j] = ldfrag(&sB[buf][(wc * 64 + j * 16 + l16) * 32 + quad * 8]);
#pragma unroll
        for (int i = 0; i < 4; ++i)
#pragma unroll
            for (int j = 0; j < 4; ++j)
                acc[i][j] = __builtin_amdgcn_mfma_f32_16x16x32_bf16(af[i], bfr[j], acc[i][j], 0, 0, 0);
    }

#pragma unroll
    for (int j = 0; j < 4; ++j) {
        int n = n0 + wc * 64 + j * 16 + l16;
        float bv_ = bo[n];
#pragma unroll
        for (int i = 0; i < 4; ++i) {
#pragma unroll
            for (int r = 0; r < 4; ++r) {
                size_t m = m0 + wr * 64 + i * 16 + quad * 4 + r;
                Hout[m * 768 + n] = f2bf(acc[i][j][r] + bv_ + X[m * 768 + n]);
            }
        }
    }
}

// ---- kernel 4: custom LayerNorm (bf16 in, fp32 out) ------------------------
__global__ __launch_bounds__(256) void lnorm(const u16* __restrict__ Hs, float* __restrict__ out)
{
    const int row = blockIdx.x;
    const u16* hr = Hs + (size_t)row * 768;
    const int tid = threadIdx.x;
    float v0 = bf2f(hr[tid]), v1 = bf2f(hr[tid + 256]), v2 = bf2f(hr[tid + 512]);
    float s = v0 + v1 + v2;
    float ss = v0 * v0 + v1 * v1 + v2 * v2;
#pragma unroll
    for (int off = 1; off < 64; off <<= 1) {
        s  += __shfl_xor(s, off);
        ss += __shfl_xor(ss, off);
    }
    __shared__ float red[8];
    const int wave = tid >> 6, lane = tid & 63;
    if (lane == 0) { red[wave] = s; red[4 + wave] = ss; }
    __syncthreads();
    s  = red[0] + red[1] + red[2] + red[3];
    ss = red[4] + red[5] + red[6] + red[7];
    float mean = s * (1.0f / 768.0f);
    float var = fmaxf((ss - 768.0f * mean * mean) * (1.0f / 767.0f), 0.0f);
    float inv = 1.0f / (sqrtf(var) + 1e-12f);
    float* orow = out + (size_t)row * 768;
    orow[tid]       = (v0 - mean) * inv;
    orow[tid + 256] = (v1 - mean) * inv;
    orow[tid + 512] = (v2 - mean) * inv;
}

// ---- launch ----------------------------------------------------------------
extern "C" void kernel_launch(void* const* d_in, const int* in_sizes, int n_in,
                              void* d_out, int out_size, void* d_ws, size_t ws_size,
                              hipStream_t stream)
{
    const float* X  = (const float*)d_in[0];
    const float* Wq = (const float*)d_in[1];
    const float* bq = (const float*)d_in[2];
    const float* Wk = (const float*)d_in[3];
    const float* bk = (const float*)d_in[4];
    const float* Wv = (const float*)d_in[5];
    const float* bv = (const float*)d_in[6];
    const float* Wo = (const float*)d_in[7];
    const float* bo = (const float*)d_in[8];
    float* out = (float*)d_out;

    const size_t TE = (size_t)8192 * 768;
    const size_t WN = (size_t)768 * 768;
    u16* ws  = (u16*)d_ws;
    u16* Xb  = ws;                 // bf16 X ; later: ctx
    u16* Qw  = ws + TE;            // bf16 Q (log2e-scaled) ; later: h (bf16)
    u16* Kw  = ws + 2 * TE;        // bf16 K
    u16* Vt  = ws + 3 * TE;        // bf16 V^T [BH][64][2048]
    u16* Wqb = ws + 4 * TE;        // Wcat[2304][768] = Wq|Wk|Wv contiguous
    u16* Wkb = Wqb + WN;
    u16* Wvb = Wqb + 2 * WN;
    u16* Wob = Wqb + 3 * WN;
    u16* Cw  = Xb;                 // ctx aliases Xb
    u16* Hw  = Qw;                 // h bf16 aliases Q

    convert<<<8448, 256, 0, stream>>>(X, Wq, Wk, Wv, Wo, Xb, Wqb, Wkb, Wvb, Wob);
    gemm_qkv<<<dim3(64, 18), 256, 0, stream>>>(Xb, Wqb, bq, bk, bv, Qw, Kw, Vt);
    attn<<<768, 256, 0, stream>>>(Qw, Kw, Vt, Cw);
    gemm_out<<<dim3(64, 6), 256, 0, stream>>>(Cw, Wob, bo, X, Hw);
    lnorm<<<8192, 256, 0, stream>>>(Hw, out);
}

// Round 9
// 252.624 us; speedup vs baseline: 1.0022x; 1.0022x over previous
//
#include <hip/hip_runtime.h>

// ---- types / helpers -------------------------------------------------------
typedef unsigned short u16;
typedef unsigned int   u32;
typedef __attribute__((ext_vector_type(4))) u32    u32x4;
typedef __attribute__((ext_vector_type(4))) u16    u16x4;
typedef __attribute__((ext_vector_type(8))) u16    u16x8;
typedef __attribute__((ext_vector_type(8))) __bf16 bf16x8;
typedef __attribute__((ext_vector_type(4))) float  f32x4;

#define LOG2E 1.4426950408889634f

__device__ __forceinline__ float bf2f(u16 x) {
    u32 u = ((u32)x) << 16;
    return __builtin_bit_cast(float, u);
}
__device__ __forceinline__ u16 f2bf(float f) {  // RNE
    u32 u = __builtin_bit_cast(u32, f);
    return (u16)((u + 0x7FFFu + ((u >> 16) & 1u)) >> 16);
}
__device__ __forceinline__ u32 pk2(float a, float b) {
#if __has_builtin(__builtin_amdgcn_cvt_pk_bf16_f32)
    return __builtin_bit_cast(u32, __builtin_amdgcn_cvt_pk_bf16_f32(a, b));
#else
    return (u32)f2bf(a) | ((u32)f2bf(b) << 16);
#endif
}
__device__ __forceinline__ u16x4 pack4(f32x4 v) {
    u32 lo = pk2(v[0], v[1]), hi = pk2(v[2], v[3]);
    u32 both[2] = {lo, hi};
    return __builtin_bit_cast(u16x4, *(unsigned long long*)both);
}
__device__ __forceinline__ float fexp2(float x) {
#if __has_builtin(__builtin_amdgcn_exp2f)
    return __builtin_amdgcn_exp2f(x);
#else
    float r;
    asm("v_exp_f32 %0, %1" : "=v"(r) : "v"(x));
    return r;
#endif
}
__device__ __forceinline__ bf16x8 ldfrag(const u16* p) {
    return __builtin_bit_cast(bf16x8, *(const u32x4*)p);
}
// async global->LDS DMA, 16 B per lane; LDS dst = base + lane*16 (wave-uniform base)
__device__ __forceinline__ void g2l16(const u16* g, u16* l) {
    __builtin_amdgcn_global_load_lds(
        (const __attribute__((address_space(1))) u32*)g,
        (__attribute__((address_space(3))) u32*)l,
        16, 0, 0);
}

// ---- kernel 0: one-shot fp32 -> bf16 conversion (Wq pre-scaled by log2e) ---
__global__ __launch_bounds__(256) void convert(
    const float* __restrict__ X,
    const float* __restrict__ Wq, const float* __restrict__ Wk,
    const float* __restrict__ Wv, const float* __restrict__ Wo,
    u16* __restrict__ Xb, u16* __restrict__ Wqb, u16* __restrict__ Wkb,
    u16* __restrict__ Wvb, u16* __restrict__ Wob)
{
    const int NX = 1572864;   // 8192*768/4
    const int NW = 147456;    // 768*768/4
    int i = blockIdx.x * 256 + threadIdx.x;
    const float* src; u16* dst; int off; float sc = 1.0f;
    if (i < NX)               { src = X;  dst = Xb;  off = i; }
    else if (i < NX + NW)     { src = Wq; dst = Wqb; off = i - NX; sc = LOG2E; }
    else if (i < NX + 2 * NW) { src = Wk; dst = Wkb; off = i - NX - NW; }
    else if (i < NX + 3 * NW) { src = Wv; dst = Wvb; off = i - NX - 2 * NW; }
    else                      { src = Wo; dst = Wob; off = i - NX - 3 * NW; }
    f32x4 v = *(const f32x4*)&src[(size_t)off * 4];
    f32x4 s4 = {sc, sc, sc, sc};
    v *= s4;
    *(u16x4*)&dst[(size_t)off * 4] = pack4(v);
}

// ---- kernel 1: unified QKV GEMM (BK=32, dbuf DMA, XOR-swizzled LDS) --------
// C[8192,2304] = Xb * Wcat^T. Q/K blocks compute C^T (swapped MFMA operands)
// so the head-major epilogue is b64-vectorized. V written transposed.
// LDS rows are unpadded 32-elem (DMA constraint); chunk c of row r is stored
// at chunk c^(r&3) -> column-fragment b128 reads are 2-way-bank (free).
__global__ __launch_bounds__(256) void gemm_qkv(
    const u16* __restrict__ Xb, const u16* __restrict__ Wcat,
    const float* __restrict__ bq, const float* __restrict__ bk, const float* __restrict__ bv,
    u16* __restrict__ Qo, u16* __restrict__ Ko, u16* __restrict__ Vt)
{
    __shared__ __align__(16) u16 sA[2][128 * 32];
    __shared__ __align__(16) u16 sB[2][128 * 32];

    const int tid = threadIdx.x;
    const int wave = tid >> 6, lane = tid & 63;
    const int quad = lane >> 4, l16 = lane & 15;
    const int wr = wave >> 1, wc = wave & 1;
    const int m0 = blockIdx.x * 128;
    const int ny = blockIdx.y;            // 0..17
    const int which = ny / 6;             // 0=Q 1=K 2=V
    const int n0 = ny * 128;
    const int n_in = (ny % 6) * 128;

    // DMA coords with XOR swizzle: issue covers 16 rows x 4 chunks (16B each)
    const int drow = wave * 32 + (lane >> 2);
    const int dcol = ((lane & 3) ^ ((lane >> 2) & 3)) * 8;   // swizzled source chunk
    const u16* gA = &Xb  [(size_t)(m0 + drow) * 768 + dcol];
    const u16* gB = &Wcat[(size_t)(n0 + drow) * 768 + dcol];
    u16* lA = &sA[0][wave * 1024];   // buf selected by +buf*4096
    u16* lB = &sB[0][wave * 1024];

    const int xq = (quad * 8) ^ ((l16 & 3) * 8);  // swizzled fragment chunk offset

    f32x4 acc[4][4] = {};

    // prologue: tile 0 -> buf 0
    g2l16(gA,            lA);
    g2l16(gA + 16 * 768, lA + 512);
    g2l16(gB,            lB);
    g2l16(gB + 16 * 768, lB + 512);

    for (int t = 0; t < 24; ++t) {
        const int buf = t & 1;
        __syncthreads();              // drains DMA(t); compute(t-1) done on buf^1
        if (t < 23) {
            const int k = (t + 1) * 32;
            u16* dA = lA + (buf ^ 1) * 4096;
            u16* dB = lB + (buf ^ 1) * 4096;
            g2l16(gA + k,            dA);
            g2l16(gA + k + 16 * 768, dA + 512);
            g2l16(gB + k,            dB);
            g2l16(gB + k + 16 * 768, dB + 512);
        }
        bf16x8 af[4], bfr[4];
#pragma unroll
        for (int i = 0; i < 4; ++i)
            af[i] = ldfrag(&sA[buf][(wr * 64 + i * 16 + l16) * 32 + xq]);
#pragma unroll
        for (int j = 0; j < 4; ++j)
            bfr[j] = ldfrag(&sB[buf][(wc * 64 + j * 16 + l16) * 32 + xq]);
        if (which < 2) {              // C^T: rows=n(hd-dir), cols=m(s)
#pragma unroll
            for (int i = 0; i < 4; ++i)
#pragma unroll
                for (int j = 0; j < 4; ++j)
                    acc[i][j] = __builtin_amdgcn_mfma_f32_16x16x32_bf16(bfr[j], af[i], acc[i][j], 0, 0, 0);
        } else {                      // C: rows=m(s), cols=n(hd)
#pragma unroll
            for (int i = 0; i < 4; ++i)
#pragma unroll
                for (int j = 0; j < 4; ++j)
                    acc[i][j] = __builtin_amdgcn_mfma_f32_16x16x32_bf16(af[i], bfr[j], acc[i][j], 0, 0, 0);
        }
    }

    const float* bias = (which == 0) ? bq : ((which == 1) ? bk : bv);
    if (which < 2) {
        u16* out = (which == 0) ? Qo : Ko;
        const float sc = (which == 0) ? LOG2E : 1.0f;   // W pre-scaled; bias here
        f32x4 sc4 = {sc, sc, sc, sc};
#pragma unroll
        for (int j = 0; j < 4; ++j) {
            int nb = n_in + wc * 64 + j * 16 + quad * 4;   // 4 consecutive n
            f32x4 b4 = *(const f32x4*)&bias[nb] * sc4;
            int h = nb >> 6, hd0 = nb & 63;
#pragma unroll
            for (int i = 0; i < 4; ++i) {
                int m = m0 + wr * 64 + i * 16 + l16;       // s
                int b = m >> 11, srow = m & 2047;
                *(u16x4*)&out[(((size_t)(b * 12 + h) * 2048) + srow) * 64 + hd0] =
                    pack4(acc[i][j] + b4);
            }
        }
    } else {
        // V^T [BH][64][S]: pack4 over r = s-direction
#pragma unroll
        for (int j = 0; j < 4; ++j) {
            int n = n_in + wc * 64 + j * 16 + l16;
            float bvv = bias[n];
            int h = n >> 6, hd = n & 63;
            f32x4 b4 = {bvv, bvv, bvv, bvv};
#pragma unroll
            for (int i = 0; i < 4; ++i) {
                int m = m0 + wr * 64 + i * 16 + quad * 4;
                int b = m >> 11, s = m & 2047;
                *(u16x4*)&Vt[((size_t)(b * 12 + h) * 64 + hd) * 2048 + s] = pack4(acc[i][j] + b4);
            }
        }
    }
}

// ---- kernel 2: flash attention v6 (dbuf DMA + XOR-swizzled K/Vt planes) ----
__global__ __launch_bounds__(256, 3) void attn(
    const u16* __restrict__ Q, const u16* __restrict__ K, const u16* __restrict__ Vt,
    u16* __restrict__ ctx)
{
    const int bid = blockIdx.x;
    const int xcd = bid & 7, slot = bid >> 3;
    const int bh = xcd * 6 + (slot % 6);      // 6 heads per XCD
    const int q0 = (slot / 6) * 128;
    const int b = bh / 12, h = bh % 12;
    const u16* Qb  = Q  + (size_t)bh * (2048 * 64);
    const u16* Kb  = K  + (size_t)bh * (2048 * 64);
    const u16* Vtb = Vt + (size_t)bh * (64 * 2048);

    __shared__ __align__(16) u16 sK [2][2][64 * 32];   // [buf][d-half][key][d32] (swizzled)
    __shared__ __align__(16) u16 sVt[2][2][64 * 32];   // [buf][key-half][hd][k32] (swizzled)
    __shared__ __align__(16) u16 sPt[128 * 72];        // [q][key], wave-private rows

    const int tid = threadIdx.x;
    const int wave = tid >> 6, lane = tid & 63;
    const int quad = lane >> 4, l16 = lane & 15;

    const int drow = lane >> 2;                              // 0..15 (+wave*16)
    const int dcol = ((lane & 3) ^ ((lane >> 2) & 3)) * 8;   // swizzled source chunk
    const int xq = (quad * 8) ^ ((l16 & 3) * 8);             // swizzled frag chunk

    // Q fragments direct to registers. B-operand: [n=q=l16][k=d=quad*8+j]
    bf16x8 qf[2][2];
#pragma unroll
    for (int jn = 0; jn < 2; ++jn)
#pragma unroll
        for (int ks = 0; ks < 2; ++ks)
            qf[jn][ks] = ldfrag(&Qb[(size_t)(q0 + wave * 32 + jn * 16 + l16) * 64 + ks * 32 + quad * 8]);

    bf16x8 vones;
    {
        u16x8 o;
#pragma unroll
        for (int t = 0; t < 8; ++t) o[t] = 0x3F80;
        vones = __builtin_bit_cast(bf16x8, o);
    }

    f32x4 oacc[2][4] = {};
    f32x4 Lacc[2] = {};

    // prologue: tile kt=0 -> buf 0
#pragma unroll
    for (int p = 0; p < 2; ++p) {
        g2l16(&Kb [(size_t)(wave * 16 + drow) * 64 + p * 32 + dcol],   &sK [0][p][wave * 512]);
        g2l16(&Vtb[(size_t)(wave * 16 + drow) * 2048 + p * 32 + dcol], &sVt[0][p][wave * 512]);
    }

    for (int kt = 0; kt < 2048; kt += 64) {
        const int buf = (kt >> 6) & 1;
        __syncthreads();              // drains DMA(buf); compute(prev) done on buf^1
        if (kt + 64 < 2048) {
            const int kn = kt + 64;
#pragma unroll
            for (int p = 0; p < 2; ++p) {
                g2l16(&Kb [(size_t)(kn + wave * 16 + drow) * 64 + p * 32 + dcol],
                      &sK [buf ^ 1][p][wave * 512]);
                g2l16(&Vtb[(size_t)(wave * 16 + drow) * 2048 + kn + p * 32 + dcol],
                      &sVt[buf ^ 1][p][wave * 512]);
            }
        }

        // S^T = K · Q^T : rows=key (4 tiles), cols=q (2 tiles of this wave)
        f32x4 sacc[4][2] = {};
#pragma unroll
        for (int ks = 0; ks < 2; ++ks) {
            bf16x8 kf[4];   // A-operand: [m=key=l16][k=d=quad*8+j]
#pragma unroll
            for (int i = 0; i < 4; ++i)
                kf[i] = ldfrag(&sK[buf][ks][(i * 16 + l16) * 32 + xq]);
#pragma unroll
            for (int i = 0; i < 4; ++i)
#pragma unroll
                for (int jn = 0; jn < 2; ++jn)
                    sacc[i][jn] = __builtin_amdgcn_mfma_f32_16x16x32_bf16(kf[i], qf[jn][ks], sacc[i][jn], 0, 0, 0);
        }

        // exp2 (log2e folded into Q) -> P bf16 into wave-private sPt rows
#pragma unroll
        for (int i = 0; i < 4; ++i) {
#pragma unroll
            for (int jn = 0; jn < 2; ++jn) {
                f32x4 pe;
#pragma unroll
                for (int r = 0; r < 4; ++r) pe[r] = fexp2(sacc[i][jn][r]);
                *(u16x4*)&sPt[(wave * 32 + jn * 16 + l16) * 72 + i * 16 + quad * 4] = pack4(pe);
            }
        }

        // O += P · V ; L += P · 1
#pragma unroll
        for (int ks2 = 0; ks2 < 2; ++ks2) {
            bf16x8 pf[2], vf[4];
#pragma unroll
            for (int jn = 0; jn < 2; ++jn)
                pf[jn] = ldfrag(&sPt[(wave * 32 + jn * 16 + l16) * 72 + ks2 * 32 + quad * 8]);
#pragma unroll
            for (int jh = 0; jh < 4; ++jh)
                vf[jh] = ldfrag(&sVt[buf][ks2][(jh * 16 + l16) * 32 + xq]);
#pragma unroll
            for (int jn = 0; jn < 2; ++jn) {
#pragma unroll
                for (int jh = 0; jh < 4; ++jh)
                    oacc[jn][jh] = __builtin_amdgcn_mfma_f32_16x16x32_bf16(pf[jn], vf[jh], oacc[jn][jh], 0, 0, 0);
                Lacc[jn] = __builtin_amdgcn_mfma_f32_16x16x32_bf16(pf[jn], vones, Lacc[jn], 0, 0, 0);
            }
        }
    }

    // epilogue: O and L share C/D layout (row q = jn*16+quad*4+r, col = l16)
#pragma unroll
    for (int jn = 0; jn < 2; ++jn) {
#pragma unroll
        for (int r = 0; r < 4; ++r) {
            float linv = 1.0f / Lacc[jn][r];
            int srow = q0 + wave * 32 + jn * 16 + quad * 4 + r;
            size_t rowbase = ((size_t)(b * 2048 + srow)) * 768 + h * 64;
#pragma unroll
            for (int jh = 0; jh < 4; ++jh)
                ctx[rowbase + jh * 16 + l16] = f2bf(oacc[jn][jh][r] * linv);
        }
    }
}

// ---- kernel 3: output projection + bias + residual (BK=32 dbuf DMA, XOR) ---
__global__ __launch_bounds__(256) void gemm_out(
    const u16* __restrict__ A,    // ctx [8192,768] bf16
    const u16* __restrict__ Wob,  // [768,768] bf16
    const float* __restrict__ bo,
    const float* __restrict__ X,  // residual fp32 (exact)
    u16* __restrict__ Hout)       // h bf16
{
    __shared__ __align__(16) u16 sA[2][128 * 32];
    __shared__ __align__(16) u16 sB[2][128 * 32];

    const int tid = threadIdx.x;
    const int wave = tid >> 6, lane = tid & 63;
    const int quad = lane >> 4, l16 = lane & 15;
    const int wr = wave >> 1, wc = wave & 1;
    const int m0 = blockIdx.x * 128, n0 = blockIdx.y * 128;

    const int drow = wave * 32 + (lane >> 2);
    const int dcol = ((lane & 3) ^ ((lane >> 2) & 3)) * 8;
    const u16* gA = &A  [(size_t)(m0 + drow) * 768 + dcol];
    const u16* gB = &Wob[(size_t)(n0 + drow) * 768 + dcol];
    u16* lA = &sA[0][wave * 1024];
    u16* lB = &sB[0][wave * 1024];

    const int xq = (quad * 8) ^ ((l16 & 3) * 8);

    f32x4 acc[4][4] = {};

    g2l16(gA,            lA);
    g2l16(gA + 16 * 768, lA + 512);
    g2l16(gB,            lB);
    g2l16(gB + 16 * 768, lB + 512);

    for (int t = 0; t < 24; ++t) {
        const int buf = t & 1;
        __syncthreads();
        if (t < 23) {
            const int k = (t + 1) * 32;
            u16* dA = lA + (buf ^ 1) * 4096;
            u16* dB = lB + (buf ^ 1) * 4096;
            g2l16(gA + k,            dA);
            g2l16(gA + k + 16 * 768, dA + 512);
            g2l16(gB + k,            dB);
            g2l16(gB + k + 16 * 768, dB + 512);
        }
        bf16x8 af[4], bfr[4];
#pragma unroll
        for (int i = 0; i < 4; ++i)
            af[i] = ldfrag(&sA[buf][(wr * 64 + i * 16 + l16) * 32 + xq]);
#pragma unroll
        for (int j = 0; j < 4; ++j)
            bfr[j] = ldfrag(&sB[buf][(wc * 64 + j * 16 + l16) * 32 + xq]);
#pragma unroll
        for (int i = 0; i < 4; ++i)
#pragma unroll
            for (int j = 0; j < 4; ++j)
                acc[i][j] = __builtin_amdgcn_mfma_f32_16x16x32_bf16(af[i], bfr[j], acc[i][j], 0, 0, 0);
    }

#pragma unroll
    for (int j = 0; j < 4; ++j) {
        int n = n0 + wc * 64 + j * 16 + l16;
        float bv_ = bo[n];
#pragma unroll
        for (int i = 0; i < 4; ++i) {
#pragma unroll
            for (int r = 0; r < 4; ++r) {
                size_t m = m0 + wr * 64 + i * 16 + quad * 4 + r;
                Hout[m * 768 + n] = f2bf(acc[i][j][r] + bv_ + X[m * 768 + n]);
            }
        }
    }
}

// ---- kernel 4: custom LayerNorm (bf16 in, fp32 out) ------------------------
__global__ __launch_bounds__(256) void lnorm(const u16* __restrict__ Hs, float* __restrict__ out)
{
    const int row = blockIdx.x;
    const u16* hr = Hs + (size_t)row * 768;
    const int tid = threadIdx.x;
    float v0 = bf2f(hr[tid]), v1 = bf2f(hr[tid + 256]), v2 = bf2f(hr[tid + 512]);
    float s = v0 + v1 + v2;
    float ss = v0 * v0 + v1 * v1 + v2 * v2;
#pragma unroll
    for (int off = 1; off < 64; off <<= 1) {
        s  += __shfl_xor(s, off);
        ss += __shfl_xor(ss, off);
    }
    __shared__ float red[8];
    const int wave = tid >> 6, lane = tid & 63;
    if (lane == 0) { red[wave] = s; red[4 + wave] = ss; }
    __syncthreads();
    s  = red[0] + red[1] + red[2] + red[3];
    ss = red[4] + red[5] + red[6] + red[7];
    float mean = s * (1.0f / 768.0f);
    float var = fmaxf((ss - 768.0f * mean * mean) * (1.0f / 767.0f), 0.0f);
    float inv = 1.0f / (sqrtf(var) + 1e-12f);
    float* orow = out + (size_t)row * 768;
    orow[tid]       = (v0 - mean) * inv;
    orow[tid + 256] = (v1 - mean) * inv;
    orow[tid + 512] = (v2 - mean) * inv;
}

// ---- launch ----------------------------------------------------------------
extern "C" void kernel_launch(void* const* d_in, const int* in_sizes, int n_in,
                              void* d_out, int out_size, void* d_ws, size_t ws_size,
                              hipStream_t stream)
{
    const float* X  = (const float*)d_in[0];
    const float* Wq = (const float*)d_in[1];
    const float* bq = (const float*)d_in[2];
    const float* Wk = (const float*)d_in[3];
    const float* bk = (const float*)d_in[4];
    const float* Wv = (const float*)d_in[5];
    const float* bv = (const float*)d_in[6];
    const float* Wo = (const float*)d_in[7];
    const float* bo = (const float*)d_in[8];
    float* out = (float*)d_out;

    const size_t TE = (size_t)8192 * 768;
    const size_t WN = (size_t)768 * 768;
    u16* ws  = (u16*)d_ws;
    u16* Xb  = ws;                 // bf16 X ; later: ctx
    u16* Qw  = ws + TE;            // bf16 Q (log2e-scaled) ; later: h (bf16)
    u16* Kw  = ws + 2 * TE;        // bf16 K
    u16* Vt  = ws + 3 * TE;        // bf16 V^T [BH][64][2048]
    u16* Wqb = ws + 4 * TE;        // Wcat[2304][768] = Wq|Wk|Wv contiguous
    u16* Wkb = Wqb + WN;
    u16* Wvb = Wqb + 2 * WN;
    u16* Wob = Wqb + 3 * WN;
    u16* Cw  = Xb;                 // ctx aliases Xb
    u16* Hw  = Qw;                 // h bf16 aliases Q

    convert<<<8448, 256, 0, stream>>>(X, Wq, Wk, Wv, Wo, Xb, Wqb, Wkb, Wvb, Wob);
    gemm_qkv<<<dim3(64, 18), 256, 0, stream>>>(Xb, Wqb, bq, bk, bv, Qw, Kw, Vt);
    attn<<<768, 256, 0, stream>>>(Qw, Kw, Vt, Cw);
    gemm_out<<<dim3(64, 6), 256, 0, stream>>>(Cw, Wob, bo, X, Hw);
    lnorm<<<8192, 256, 0, stream>>>(Hw, out);
}

// Round 10
// 237.707 us; speedup vs baseline: 1.0651x; 1.0628x over previous
//
#include <hip/hip_runtime.h>

// ---- types / helpers -------------------------------------------------------
typedef unsigned short u16;
typedef unsigned int   u32;
typedef __attribute__((ext_vector_type(4))) u32    u32x4;
typedef __attribute__((ext_vector_type(4))) u16    u16x4;
typedef __attribute__((ext_vector_type(8))) u16    u16x8;
typedef __attribute__((ext_vector_type(8))) __bf16 bf16x8;
typedef __attribute__((ext_vector_type(4))) float  f32x4;

#define LOG2E 1.4426950408889634f

__device__ __forceinline__ float bf2f(u16 x) {
    u32 u = ((u32)x) << 16;
    return __builtin_bit_cast(float, u);
}
__device__ __forceinline__ u16 f2bf(float f) {  // RNE
    u32 u = __builtin_bit_cast(u32, f);
    return (u16)((u + 0x7FFFu + ((u >> 16) & 1u)) >> 16);
}
__device__ __forceinline__ u32 pk2(float a, float b) {
#if __has_builtin(__builtin_amdgcn_cvt_pk_bf16_f32)
    return __builtin_bit_cast(u32, __builtin_amdgcn_cvt_pk_bf16_f32(a, b));
#else
    return (u32)f2bf(a) | ((u32)f2bf(b) << 16);
#endif
}
__device__ __forceinline__ u16x4 pack4(f32x4 v) {
    u32 lo = pk2(v[0], v[1]), hi = pk2(v[2], v[3]);
    u32 both[2] = {lo, hi};
    return __builtin_bit_cast(u16x4, *(unsigned long long*)both);
}
__device__ __forceinline__ float fexp2(float x) {
#if __has_builtin(__builtin_amdgcn_exp2f)
    return __builtin_amdgcn_exp2f(x);
#else
    float r;
    asm("v_exp_f32 %0, %1" : "=v"(r) : "v"(x));
    return r;
#endif
}
__device__ __forceinline__ bf16x8 ldfrag(const u16* p) {
    return __builtin_bit_cast(bf16x8, *(const u32x4*)p);
}
// async global->LDS DMA, 16 B per lane; LDS dst = base + lane*16 (wave-uniform base)
__device__ __forceinline__ void g2l16(const u16* g, u16* l) {
    __builtin_amdgcn_global_load_lds(
        (const __attribute__((address_space(1))) u32*)g,
        (__attribute__((address_space(3))) u32*)l,
        16, 0, 0);
}

// ---- kernel 0: one-shot fp32 -> bf16 conversion (Wq pre-scaled by log2e) ---
__global__ __launch_bounds__(256) void convert(
    const float* __restrict__ X,
    const float* __restrict__ Wq, const float* __restrict__ Wk,
    const float* __restrict__ Wv, const float* __restrict__ Wo,
    u16* __restrict__ Xb, u16* __restrict__ Wqb, u16* __restrict__ Wkb,
    u16* __restrict__ Wvb, u16* __restrict__ Wob)
{
    const int NX = 1572864;   // 8192*768/4
    const int NW = 147456;    // 768*768/4
    int i = blockIdx.x * 256 + threadIdx.x;
    const float* src; u16* dst; int off; float sc = 1.0f;
    if (i < NX)               { src = X;  dst = Xb;  off = i; }
    else if (i < NX + NW)     { src = Wq; dst = Wqb; off = i - NX; sc = LOG2E; }
    else if (i < NX + 2 * NW) { src = Wk; dst = Wkb; off = i - NX - NW; }
    else if (i < NX + 3 * NW) { src = Wv; dst = Wvb; off = i - NX - 2 * NW; }
    else                      { src = Wo; dst = Wob; off = i - NX - 3 * NW; }
    f32x4 v = *(const f32x4*)&src[(size_t)off * 4];
    f32x4 s4 = {sc, sc, sc, sc};
    v *= s4;
    *(u16x4*)&dst[(size_t)off * 4] = pack4(v);
}

// ---- kernel 1: unified QKV GEMM (BK=64, reg-prefetch, stride-80 LDS) -------
// C[8192,2304] = Xb * Wcat^T. Q/K blocks compute C^T (swapped MFMA operands)
// -> head-major epilogue is b64-vectorized. V written transposed.
// LDS stride 80 u16 (40 dwords): fragment b128 reads land 8 accesses/bank
// (the wave64 minimum, conflict-free); stride-72's 4*(l16+quad) 8-way is gone.
__global__ __launch_bounds__(256) void gemm_qkv(
    const u16* __restrict__ Xb, const u16* __restrict__ Wcat,
    const float* __restrict__ bq, const float* __restrict__ bk, const float* __restrict__ bv,
    u16* __restrict__ Qo, u16* __restrict__ Ko, u16* __restrict__ Vt)
{
    __shared__ __align__(16) u16 sA[128 * 80];
    __shared__ __align__(16) u16 sB[128 * 80];

    const int tid = threadIdx.x;
    const int wave = tid >> 6, lane = tid & 63;
    const int quad = lane >> 4, l16 = lane & 15;
    const int wr = wave >> 1, wc = wave & 1;
    const int m0 = blockIdx.x * 128;
    const int ny = blockIdx.y;            // 0..17
    const int which = ny / 6;             // 0=Q 1=K 2=V
    const int n0 = ny * 128;
    const int n_in = (ny % 6) * 128;

    // staging coords: chunk c = p*256+tid -> row c>>3, col (c&7)*8
    int rr[4], cc[4];
#pragma unroll
    for (int p = 0; p < 4; ++p) { int c = p * 256 + tid; rr[p] = c >> 3; cc[p] = (c & 7) * 8; }

    f32x4 acc[4][4] = {};
    u32x4 ra[4], rb[4];
#pragma unroll
    for (int p = 0; p < 4; ++p) {
        ra[p] = *(const u32x4*)&Xb  [(size_t)(m0 + rr[p]) * 768 + cc[p]];
        rb[p] = *(const u32x4*)&Wcat[(size_t)(n0 + rr[p]) * 768 + cc[p]];
    }

    for (int k0 = 0; k0 < 768; k0 += 64) {
        __syncthreads();                   // prev compute done reading sA/sB
#pragma unroll
        for (int p = 0; p < 4; ++p) {
            *(u32x4*)&sA[rr[p] * 80 + cc[p]] = ra[p];
            *(u32x4*)&sB[rr[p] * 80 + cc[p]] = rb[p];
        }
        int kn = k0 + 64; if (kn == 768) kn = 0;   // wrapped prefetch
#pragma unroll
        for (int p = 0; p < 4; ++p) {
            ra[p] = *(const u32x4*)&Xb  [(size_t)(m0 + rr[p]) * 768 + kn + cc[p]];
            rb[p] = *(const u32x4*)&Wcat[(size_t)(n0 + rr[p]) * 768 + kn + cc[p]];
        }
        __syncthreads();                   // staging visible

#pragma unroll
        for (int ks = 0; ks < 2; ++ks) {
            bf16x8 af[4], bfr[4];
#pragma unroll
            for (int i = 0; i < 4; ++i)
                af[i] = ldfrag(&sA[(wr * 64 + i * 16 + l16) * 80 + ks * 32 + quad * 8]);
#pragma unroll
            for (int j = 0; j < 4; ++j)
                bfr[j] = ldfrag(&sB[(wc * 64 + j * 16 + l16) * 80 + ks * 32 + quad * 8]);
            if (which < 2) {               // C^T: rows=n(hd-dir), cols=m(s)
#pragma unroll
                for (int i = 0; i < 4; ++i)
#pragma unroll
                    for (int j = 0; j < 4; ++j)
                        acc[i][j] = __builtin_amdgcn_mfma_f32_16x16x32_bf16(bfr[j], af[i], acc[i][j], 0, 0, 0);
            } else {                       // C: rows=m(s), cols=n(hd)
#pragma unroll
                for (int i = 0; i < 4; ++i)
#pragma unroll
                    for (int j = 0; j < 4; ++j)
                        acc[i][j] = __builtin_amdgcn_mfma_f32_16x16x32_bf16(af[i], bfr[j], acc[i][j], 0, 0, 0);
            }
        }
    }

    const float* bias = (which == 0) ? bq : ((which == 1) ? bk : bv);
    if (which < 2) {
        u16* out = (which == 0) ? Qo : Ko;
        const float sc = (which == 0) ? LOG2E : 1.0f;   // W pre-scaled; bias here
        f32x4 sc4 = {sc, sc, sc, sc};
#pragma unroll
        for (int j = 0; j < 4; ++j) {
            int nb = n_in + wc * 64 + j * 16 + quad * 4;   // 4 consecutive n
            f32x4 b4 = *(const f32x4*)&bias[nb] * sc4;
            int h = nb >> 6, hd0 = nb & 63;
#pragma unroll
            for (int i = 0; i < 4; ++i) {
                int m = m0 + wr * 64 + i * 16 + l16;       // s
                int b = m >> 11, srow = m & 2047;
                *(u16x4*)&out[(((size_t)(b * 12 + h) * 2048) + srow) * 64 + hd0] =
                    pack4(acc[i][j] + b4);
            }
        }
    } else {
        // V^T [BH][64][S]: pack4 over r = s-direction
#pragma unroll
        for (int j = 0; j < 4; ++j) {
            int n = n_in + wc * 64 + j * 16 + l16;
            float bvv = bias[n];
            int h = n >> 6, hd = n & 63;
            f32x4 b4 = {bvv, bvv, bvv, bvv};
#pragma unroll
            for (int i = 0; i < 4; ++i) {
                int m = m0 + wr * 64 + i * 16 + quad * 4;
                int b = m >> 11, s = m & 2047;
                *(u16x4*)&Vt[((size_t)(b * 12 + h) * 64 + hd) * 2048 + s] = pack4(acc[i][j] + b4);
            }
        }
    }
}

// ---- kernel 2: flash attention v7 (DMA K/Vt, sPt stride 80) ----------------
__global__ __launch_bounds__(256, 3) void attn(
    const u16* __restrict__ Q, const u16* __restrict__ K, const u16* __restrict__ Vt,
    u16* __restrict__ ctx)
{
    const int bid = blockIdx.x;
    const int xcd = bid & 7, slot = bid >> 3;
    const int bh = xcd * 6 + (slot % 6);      // 6 heads per XCD
    const int q0 = (slot / 6) * 128;
    const int b = bh / 12, h = bh % 12;
    const u16* Qb  = Q  + (size_t)bh * (2048 * 64);
    const u16* Kb  = K  + (size_t)bh * (2048 * 64);
    const u16* Vtb = Vt + (size_t)bh * (64 * 2048);

    __shared__ __align__(16) u16 sK [2][2][64 * 32];   // [buf][d-half][key][d32] (xq-swizzled)
    __shared__ __align__(16) u16 sVt[2][2][64 * 32];   // [buf][key-half][hd][k32] (xq-swizzled)
    __shared__ __align__(16) u16 sPt[128 * 80];        // [q][key], stride 80: conflict-free

    const int tid = threadIdx.x;
    const int wave = tid >> 6, lane = tid & 63;
    const int quad = lane >> 4, l16 = lane & 15;

    const int drow = lane >> 2;                              // 0..15 (+wave*16)
    const int dcol = ((lane & 3) ^ ((lane >> 2) & 3)) * 8;   // swizzled source chunk
    const int xq = (quad * 8) ^ ((l16 & 3) * 8);             // swizzled frag chunk

    // Q fragments direct to registers. B-operand: [n=q=l16][k=d=quad*8+j]
    bf16x8 qf[2][2];
#pragma unroll
    for (int jn = 0; jn < 2; ++jn)
#pragma unroll
        for (int ks = 0; ks < 2; ++ks)
            qf[jn][ks] = ldfrag(&Qb[(size_t)(q0 + wave * 32 + jn * 16 + l16) * 64 + ks * 32 + quad * 8]);

    bf16x8 vones;
    {
        u16x8 o;
#pragma unroll
        for (int t = 0; t < 8; ++t) o[t] = 0x3F80;
        vones = __builtin_bit_cast(bf16x8, o);
    }

    f32x4 oacc[2][4] = {};
    f32x4 Lacc[2] = {};

    // prologue: tile kt=0 -> buf 0
#pragma unroll
    for (int p = 0; p < 2; ++p) {
        g2l16(&Kb [(size_t)(wave * 16 + drow) * 64 + p * 32 + dcol],   &sK [0][p][wave * 512]);
        g2l16(&Vtb[(size_t)(wave * 16 + drow) * 2048 + p * 32 + dcol], &sVt[0][p][wave * 512]);
    }

    for (int kt = 0; kt < 2048; kt += 64) {
        const int buf = (kt >> 6) & 1;
        __syncthreads();              // drains DMA(buf); compute(prev) done on buf^1
        if (kt + 64 < 2048) {
            const int kn = kt + 64;
#pragma unroll
            for (int p = 0; p < 2; ++p) {
                g2l16(&Kb [(size_t)(kn + wave * 16 + drow) * 64 + p * 32 + dcol],
                      &sK [buf ^ 1][p][wave * 512]);
                g2l16(&Vtb[(size_t)(wave * 16 + drow) * 2048 + kn + p * 32 + dcol],
                      &sVt[buf ^ 1][p][wave * 512]);
            }
        }

        // S^T = K · Q^T : rows=key (4 tiles), cols=q (2 tiles of this wave)
        f32x4 sacc[4][2] = {};
#pragma unroll
        for (int ks = 0; ks < 2; ++ks) {
            bf16x8 kf[4];   // A-operand: [m=key=l16][k=d=quad*8+j]
#pragma unroll
            for (int i = 0; i < 4; ++i)
                kf[i] = ldfrag(&sK[buf][ks][(i * 16 + l16) * 32 + xq]);
#pragma unroll
            for (int i = 0; i < 4; ++i)
#pragma unroll
                for (int jn = 0; jn < 2; ++jn)
                    sacc[i][jn] = __builtin_amdgcn_mfma_f32_16x16x32_bf16(kf[i], qf[jn][ks], sacc[i][jn], 0, 0, 0);
        }

        // exp2 (log2e folded into Q) -> P bf16 into wave-private sPt rows
#pragma unroll
        for (int i = 0; i < 4; ++i) {
#pragma unroll
            for (int jn = 0; jn < 2; ++jn) {
                f32x4 pe;
#pragma unroll
                for (int r = 0; r < 4; ++r) pe[r] = fexp2(sacc[i][jn][r]);
                *(u16x4*)&sPt[(wave * 32 + jn * 16 + l16) * 80 + i * 16 + quad * 4] = pack4(pe);
            }
        }

        // O += P · V ; L += P · 1
#pragma unroll
        for (int ks2 = 0; ks2 < 2; ++ks2) {
            bf16x8 pf[2], vf[4];
#pragma unroll
            for (int jn = 0; jn < 2; ++jn)
                pf[jn] = ldfrag(&sPt[(wave * 32 + jn * 16 + l16) * 80 + ks2 * 32 + quad * 8]);
#pragma unroll
            for (int jh = 0; jh < 4; ++jh)
                vf[jh] = ldfrag(&sVt[buf][ks2][(jh * 16 + l16) * 32 + xq]);
#pragma unroll
            for (int jn = 0; jn < 2; ++jn) {
#pragma unroll
                for (int jh = 0; jh < 4; ++jh)
                    oacc[jn][jh] = __builtin_amdgcn_mfma_f32_16x16x32_bf16(pf[jn], vf[jh], oacc[jn][jh], 0, 0, 0);
                Lacc[jn] = __builtin_amdgcn_mfma_f32_16x16x32_bf16(pf[jn], vones, Lacc[jn], 0, 0, 0);
            }
        }
    }

    // epilogue: O and L share C/D layout (row q = jn*16+quad*4+r, col = l16)
#pragma unroll
    for (int jn = 0; jn < 2; ++jn) {
#pragma unroll
        for (int r = 0; r < 4; ++r) {
            float linv = 1.0f / Lacc[jn][r];
            int srow = q0 + wave * 32 + jn * 16 + quad * 4 + r;
            size_t rowbase = ((size_t)(b * 2048 + srow)) * 768 + h * 64;
#pragma unroll
            for (int jh = 0; jh < 4; ++jh)
                ctx[rowbase + jh * 16 + l16] = f2bf(oacc[jn][jh][r] * linv);
        }
    }
}

// ---- kernel 3: output projection + bias + residual (BK=64, stride 80) ------
__global__ __launch_bounds__(256) void gemm_out(
    const u16* __restrict__ A,    // ctx [8192,768] bf16
    const u16* __restrict__ Wob,  // [768,768] bf16
    const float* __restrict__ bo,
    const float* __restrict__ X,  // residual fp32 (exact)
    u16* __restrict__ Hout)       // h bf16
{
    __shared__ __align__(16) u16 sA[128 * 80];
    __shared__ __align__(16) u16 sB[128 * 80];

    const int tid = threadIdx.x;
    const int wave = tid >> 6, lane = tid & 63;
    const int quad = lane >> 4, l16 = lane & 15;
    const int wr = wave >> 1, wc = wave & 1;
    const int m0 = blockIdx.x * 128, n0 = blockIdx.y * 128;

    int rr[4], cc[4];
#pragma unroll
    for (int p = 0; p < 4; ++p) { int c = p * 256 + tid; rr[p] = c >> 3; cc[p] = (c & 7) * 8; }

    f32x4 acc[4][4] = {};
    u32x4 ra[4], rb[4];
#pragma unroll
    for (int p = 0; p < 4; ++p) {
        ra[p] = *(const u32x4*)&A  [(size_t)(m0 + rr[p]) * 768 + cc[p]];
        rb[p] = *(const u32x4*)&Wob[(size_t)(n0 + rr[p]) * 768 + cc[p]];
    }

    for (int k0 = 0; k0 < 768; k0 += 64) {
        __syncthreads();
#pragma unroll
        for (int p = 0; p < 4; ++p) {
            *(u32x4*)&sA[rr[p] * 80 + cc[p]] = ra[p];
            *(u32x4*)&sB[rr[p] * 80 + cc[p]] = rb[p];
        }
        int kn = k0 + 64; if (kn == 768) kn = 0;
#pragma unroll
        for (int p = 0; p < 4; ++p) {
            ra[p] = *(const u32x4*)&A  [(size_t)(m0 + rr[p]) * 768 + kn + cc[p]];
            rb[p] = *(const u32x4*)&Wob[(size_t)(n0 + rr[p]) * 768 + kn + cc[p]];
        }
        __syncthreads();

#pragma unroll
        for (int ks = 0; ks < 2; ++ks) {
            bf16x8 af[4], bfr[4];
#pragma unroll
            for (int i = 0; i < 4; ++i)
                af[i] = ldfrag(&sA[(wr * 64 + i * 16 + l16) * 80 + ks * 32 + quad * 8]);
#pragma unroll
            for (int j = 0; j < 4; ++j)
                bfr[j] = ldfrag(&sB[(wc * 64 + j * 16 + l16) * 80 + ks * 32 + quad * 8]);
#pragma unroll
            for (int i = 0; i < 4; ++i)
#pragma unroll
                for (int j = 0; j < 4; ++j)
                    acc[i][j] = __builtin_amdgcn_mfma_f32_16x16x32_bf16(af[i], bfr[j], acc[i][j], 0, 0, 0);
        }
    }

#pragma unroll
    for (int j = 0; j < 4; ++j) {
        int n = n0 + wc * 64 + j * 16 + l16;
        float bv_ = bo[n];
#pragma unroll
        for (int i = 0; i < 4; ++i) {
#pragma unroll
            for (int r = 0; r < 4; ++r) {
                size_t m = m0 + wr * 64 + i * 16 + quad * 4 + r;
                Hout[m * 768 + n] = f2bf(acc[i][j][r] + bv_ + X[m * 768 + n]);
            }
        }
    }
}

// ---- kernel 4: custom LayerNorm (bf16 in, fp32 out) ------------------------
__global__ __launch_bounds__(256) void lnorm(const u16* __restrict__ Hs, float* __restrict__ out)
{
    const int row = blockIdx.x;
    const u16* hr = Hs + (size_t)row * 768;
    const int tid = threadIdx.x;
    float v0 = bf2f(hr[tid]), v1 = bf2f(hr[tid + 256]), v2 = bf2f(hr[tid + 512]);
    float s = v0 + v1 + v2;
    float ss = v0 * v0 + v1 * v1 + v2 * v2;
#pragma unroll
    for (int off = 1; off < 64; off <<= 1) {
        s  += __shfl_xor(s, off);
        ss += __shfl_xor(ss, off);
    }
    __shared__ float red[8];
    const int wave = tid >> 6, lane = tid & 63;
    if (lane == 0) { red[wave] = s; red[4 + wave] = ss; }
    __syncthreads();
    s  = red[0] + red[1] + red[2] + red[3];
    ss = red[4] + red[5] + red[6] + red[7];
    float mean = s * (1.0f / 768.0f);
    float var = fmaxf((ss - 768.0f * mean * mean) * (1.0f / 767.0f), 0.0f);
    float inv = 1.0f / (sqrtf(var) + 1e-12f);
    float* orow = out + (size_t)row * 768;
    orow[tid]       = (v0 - mean) * inv;
    orow[tid + 256] = (v1 - mean) * inv;
    orow[tid + 512] = (v2 - mean) * inv;
}

// ---- launch ----------------------------------------------------------------
extern "C" void kernel_launch(void* const* d_in, const int* in_sizes, int n_in,
                              void* d_out, int out_size, void* d_ws, size_t ws_size,
                              hipStream_t stream)
{
    const float* X  = (const float*)d_in[0];
    const float* Wq = (const float*)d_in[1];
    const float* bq = (const float*)d_in[2];
    const float* Wk = (const float*)d_in[3];
    const float* bk = (const float*)d_in[4];
    const float* Wv = (const float*)d_in[5];
    const float* bv = (const float*)d_in[6];
    const float* Wo = (const float*)d_in[7];
    const float* bo = (const float*)d_in[8];
    float* out = (float*)d_out;

    const size_t TE = (size_t)8192 * 768;
    const size_t WN = (size_t)768 * 768;
    u16* ws  = (u16*)d_ws;
    u16* Xb  = ws;                 // bf16 X ; later: ctx
    u16* Qw  = ws + TE;            // bf16 Q (log2e-scaled) ; later: h (bf16)
    u16* Kw  = ws + 2 * TE;        // bf16 K
    u16* Vt  = ws + 3 * TE;        // bf16 V^T [BH][64][2048]
    u16* Wqb = ws + 4 * TE;        // Wcat[2304][768] = Wq|Wk|Wv contiguous
    u16* Wkb = Wqb + WN;
    u16* Wvb = Wqb + 2 * WN;
    u16* Wob = Wqb + 3 * WN;
    u16* Cw  = Xb;                 // ctx aliases Xb
    u16* Hw  = Qw;                 // h bf16 aliases Q

    convert<<<8448, 256, 0, stream>>>(X, Wq, Wk, Wv, Wo, Xb, Wqb, Wkb, Wvb, Wob);
    gemm_qkv<<<dim3(64, 18), 256, 0, stream>>>(Xb, Wqb, bq, bk, bv, Qw, Kw, Vt);
    attn<<<768, 256, 0, stream>>>(Qw, Kw, Vt, Cw);
    gemm_out<<<dim3(64, 6), 256, 0, stream>>>(Cw, Wob, bo, X, Hw);
    lnorm<<<8192, 256, 0, stream>>>(Hw, out);
}